// Round 13
// baseline (368.115 us; speedup 1.0000x reference)
//
#include <hip/hip_runtime.h>
#include <hip/hip_bf16.h>

// GNN: 2-layer GraphConv (DGL norm='both'), N=100000, E=1600000.
// Round 13: (a) k_place 512thr/1024-edge chunks -> 1563 blocks: r12's 86us
// place was chain-latency-bound (VALU 1.1%, occ 54%, 391 blocks); shorter
// per-thread atomic chains + 4x blocks. Reservation grows to 612k atomics
// over 782 line-padded counters (~10us serial floor by r7 arithmetic — safe).
// (b) agg kernels gather uint2 (8B/lane): 4 edges/VMEM (agg64), 8 edges/VMEM
// (agg32); halves VMEM instrs, doubles bytes in flight. No atomics in agg
// (LDS float atomics are dead on gfx950: r5/r11 ~680us at any occupancy).

#define BSH 7                 // 128 nodes per bucket
#define BNODES 128
#define SRCMASK 0x1FFFF       // src < 131072
#define CAP 2560              // bucket capacity (mean 2048, sigma~45)

__device__ __forceinline__ unsigned short f2bf(float f) {
    unsigned int u = __float_as_uint(f);
    return (unsigned short)((u + 0x7FFFu + ((u >> 16) & 1u)) >> 16);  // RNE
}

// ---------------- place: bin edges into fixed-cap bucket regions ------------
// 512 thr, 1024-edge chunk (2 edges/thread/phase). Phase 1 also counts
// out-degree (fire-and-forget 100k-target atomics). bcur relative, zero-init.
__global__ __launch_bounds__(512) void k_place(const int* __restrict__ src,
        const int* __restrict__ dst, int* __restrict__ bcur,
        int* __restrict__ ebuf, int* __restrict__ dO, int E, int NB) {
    __shared__ int lh[800], lbase[800];
    int t = threadIdx.x;
    int e0 = blockIdx.x * 1024;
    int e1 = min(e0 + 1024, E);
    for (int i = t; i < NB; i += 512) lh[i] = 0;
    __syncthreads();
    for (int i = e0 + t; i < e1; i += 512) {
        atomicAdd(&lh[dst[i] >> BSH], 1);
        atomicAdd(&dO[src[i]], 1);
    }
    __syncthreads();
    for (int i = t; i < NB; i += 512) {
        int c = lh[i];
        if (c) lbase[i] = atomicAdd(&bcur[i * 16], c);
        lh[i] = 0;
    }
    __syncthreads();
    for (int i = e0 + t; i < e1; i += 512) {
        int d = dst[i], b = d >> BSH;
        int pos = b * CAP + lbase[b] + atomicAdd(&lh[b], 1);
        ebuf[pos] = src[i] | ((d & (BNODES - 1)) << 17);
    }
}

// ---------------- sort2: bucket stream -> per-node CSR + ostart/oend + nI ---
__global__ __launch_bounds__(1024) void k_sort2(const int* __restrict__ ebuf,
        const int* __restrict__ bcur, int* __restrict__ csrc,
        int* __restrict__ ostart, int* __restrict__ oend,
        float* __restrict__ nI, int n) {
    __shared__ int cnt[BNODES], cur[BNODES], s[BNODES];
    int t = threadIdx.x, b = blockIdx.x;
    int e0 = b * CAP, e1 = e0 + bcur[b * 16];
    if (t < BNODES) cnt[t] = 0;
    __syncthreads();
    for (int i = e0 + t; i < e1; i += 1024)
        atomicAdd(&cnt[ebuf[i] >> 17], 1);
    __syncthreads();
    if (t < BNODES) s[t] = cnt[t];
    __syncthreads();
    for (int o = 1; o < BNODES; o <<= 1) {
        int u = (t < BNODES && t >= o) ? s[t - o] : 0;
        __syncthreads();
        if (t < BNODES) s[t] += u;
        __syncthreads();
    }
    if (t < BNODES) {
        int st = e0 + s[t] - cnt[t];
        cur[t] = st;
        int g = b * BNODES + t;
        if (g < n) {
            ostart[g] = st;
            oend[g] = e0 + s[t];
            nI[g] = rsqrtf(fmaxf((float)cnt[t], 1.0f));
        }
    }
    __syncthreads();
    for (int i = e0 + t; i < e1; i += 1024) {
        int p = ebuf[i];
        int pos = atomicAdd(&cur[p >> 17], 1);
        csrc[pos] = p & SRCMASK;
    }
}

// ---------------- GEMM1: h1(bf16) = (x*rsqrt(dO)) @ W1, 128->64 -------------
__global__ __launch_bounds__(256) void k_gemm1(const float* __restrict__ x,
                        const float* __restrict__ W1, const int* __restrict__ dO,
                        unsigned short* __restrict__ h1, int n) {
    __shared__ float sX[64 * 132];
    __shared__ float sW[128 * 64];
    const int t = threadIdx.x;
    {
        const float4* W4 = (const float4*)W1;
        float4* sW4 = (float4*)sW;
#pragma unroll
        for (int i = 0; i < 8; i++) sW4[t + 256 * i] = W4[t + 256 * i];
    }
    const int rowbase = blockIdx.x * 64;
    {
        const float4* x4 = (const float4*)x;
        float4* sX4 = (float4*)sX;
#pragma unroll
        for (int i = 0; i < 8; i++) {
            int f = t + 256 * i;
            int row = f >> 5, kc = f & 31;
            int grow = rowbase + row;
            float4 v = make_float4(0.f, 0.f, 0.f, 0.f);
            if (grow < n) v = x4[(size_t)grow * 32 + kc];
            sX4[row * 33 + kc] = v;
        }
    }
    __syncthreads();
    const int lane = t & 63, wv = t >> 6;
    const int rg = lane >> 2, cg = lane & 3;
    const int c0 = wv * 16 + cg * 4;
    float acc[4][4] = {};
    for (int kk = 0; kk < 128; kk += 4) {
        float xr[4][4], wr[4][4];
#pragma unroll
        for (int i = 0; i < 4; i++)
            *(float4*)xr[i] = *(const float4*)&sX[(rg + 16 * i) * 132 + kk];
#pragma unroll
        for (int j = 0; j < 4; j++)
            *(float4*)wr[j] = *(const float4*)&sW[(kk + j) * 64 + c0];
#pragma unroll
        for (int j = 0; j < 4; j++)
#pragma unroll
            for (int i = 0; i < 4; i++)
#pragma unroll
                for (int c = 0; c < 4; c++)
                    acc[i][c] = fmaf(xr[i][j], wr[j][c], acc[i][c]);
    }
#pragma unroll
    for (int i = 0; i < 4; i++) {
        int grow = rowbase + rg + 16 * i;
        if (grow < n) {
            float nf = rsqrtf(fmaxf((float)dO[grow], 1.0f));
            ushort4 o;
            o.x = f2bf(acc[i][0] * nf); o.y = f2bf(acc[i][1] * nf);
            o.z = f2bf(acc[i][2] * nf); o.w = f2bf(acc[i][3] * nf);
            *(ushort4*)&h1[(size_t)grow * 64 + c0] = o;
        }
    }
}

// ---------------- agg1: wave/node, uint2 loads = 4 edges/VMEM ---------------
// sub=lane>>4 (0..3) picks edge, c4=(lane&15)*4 picks 4-col group (uint2).
__global__ void k_agg64(const unsigned short* __restrict__ h,
                        const int* __restrict__ csrc,
                        const int* __restrict__ ostart, const int* __restrict__ oend,
                        const float* __restrict__ nI, const float* __restrict__ b1,
                        float* __restrict__ x2, int n) {
    int node = blockIdx.x * 4 + (threadIdx.x >> 6);
    int lane = threadIdx.x & 63;
    if (node >= n) return;
    int s0 = ostart[node], s1 = oend[node];
    int sub = lane >> 4;
    int c4 = (lane & 15) * 4;
    float a0 = 0.f, a1 = 0.f, a2 = 0.f, a3 = 0.f;
    float d0 = 0.f, d1 = 0.f, d2 = 0.f, d3 = 0.f;
    int e = s0;
    for (; e + 7 < s1; e += 8) {                 // 8 edges, 2 uint2 loads/lane
        int p0 = csrc[e + sub];
        int p1 = csrc[e + 4 + sub];
        uint2 u0 = *(const uint2*)&h[(size_t)p0 * 64 + c4];
        uint2 u1 = *(const uint2*)&h[(size_t)p1 * 64 + c4];
        a0 += __uint_as_float(u0.x << 16);
        a1 += __uint_as_float(u0.x & 0xFFFF0000u);
        a2 += __uint_as_float(u0.y << 16);
        a3 += __uint_as_float(u0.y & 0xFFFF0000u);
        d0 += __uint_as_float(u1.x << 16);
        d1 += __uint_as_float(u1.x & 0xFFFF0000u);
        d2 += __uint_as_float(u1.y << 16);
        d3 += __uint_as_float(u1.y & 0xFFFF0000u);
    }
    for (; e < s1; e += 4) {                     // tail, 4-edge groups guarded
        if (e + sub < s1) {
            int p = csrc[e + sub];
            uint2 u = *(const uint2*)&h[(size_t)p * 64 + c4];
            a0 += __uint_as_float(u.x << 16);
            a1 += __uint_as_float(u.x & 0xFFFF0000u);
            a2 += __uint_as_float(u.y << 16);
            a3 += __uint_as_float(u.y & 0xFFFF0000u);
        }
    }
    a0 += d0; a1 += d1; a2 += d2; a3 += d3;
    a0 += __shfl(a0, lane ^ 16, 64);
    a1 += __shfl(a1, lane ^ 16, 64);
    a2 += __shfl(a2, lane ^ 16, 64);
    a3 += __shfl(a3, lane ^ 16, 64);
    a0 += __shfl(a0, lane ^ 32, 64);
    a1 += __shfl(a1, lane ^ 32, 64);
    a2 += __shfl(a2, lane ^ 32, 64);
    a3 += __shfl(a3, lane ^ 32, 64);
    if (sub == 0) {
        float ni = nI[node];
        float4 o;
        o.x = fmaxf(fmaf(a0, ni, b1[c4 + 0]), 0.f);
        o.y = fmaxf(fmaf(a1, ni, b1[c4 + 1]), 0.f);
        o.z = fmaxf(fmaf(a2, ni, b1[c4 + 2]), 0.f);
        o.w = fmaxf(fmaf(a3, ni, b1[c4 + 3]), 0.f);
        *(float4*)&x2[(size_t)node * 64 + c4] = o;
    }
}

// ---------------- GEMM2: h2(bf16) = (x2*rsqrt(dO)) @ W2, 64->32 -------------
__global__ __launch_bounds__(256) void k_gemm2(const float* __restrict__ x2,
                        const float* __restrict__ W2, const int* __restrict__ dO,
                        unsigned short* __restrict__ h2, int n) {
    __shared__ float sX[128 * 68];
    __shared__ float sW[64 * 32];
    const int t = threadIdx.x;
    {
        const float4* W4 = (const float4*)W2;
        float4* sW4 = (float4*)sW;
#pragma unroll
        for (int i = 0; i < 2; i++) sW4[t + 256 * i] = W4[t + 256 * i];
    }
    const int rowbase = blockIdx.x * 128;
    {
        const float4* x4 = (const float4*)x2;
        float4* sX4 = (float4*)sX;
#pragma unroll
        for (int i = 0; i < 8; i++) {
            int f = t + 256 * i;
            int row = f >> 4, kc = f & 15;
            int grow = rowbase + row;
            float4 v = make_float4(0.f, 0.f, 0.f, 0.f);
            if (grow < n) v = x4[(size_t)grow * 16 + kc];
            sX4[row * 17 + kc] = v;
        }
    }
    __syncthreads();
    const int lane = t & 63, wv = t >> 6;
    const int whalf = wv >> 1, chalf = wv & 1;
    const int rg = lane >> 2, cg = lane & 3;
    const int c0 = chalf * 16 + cg * 4;
    const int rloc = whalf * 64 + rg;
    float acc[4][4] = {};
    for (int kk = 0; kk < 64; kk += 4) {
        float xr[4][4], wr[4][4];
#pragma unroll
        for (int i = 0; i < 4; i++)
            *(float4*)xr[i] = *(const float4*)&sX[(rloc + 16 * i) * 68 + kk];
#pragma unroll
        for (int j = 0; j < 4; j++)
            *(float4*)wr[j] = *(const float4*)&sW[(kk + j) * 32 + c0];
#pragma unroll
        for (int j = 0; j < 4; j++)
#pragma unroll
            for (int i = 0; i < 4; i++)
#pragma unroll
                for (int c = 0; c < 4; c++)
                    acc[i][c] = fmaf(xr[i][j], wr[j][c], acc[i][c]);
    }
#pragma unroll
    for (int i = 0; i < 4; i++) {
        int grow = rowbase + rloc + 16 * i;
        if (grow < n) {
            float nf = rsqrtf(fmaxf((float)dO[grow], 1.0f));
            ushort4 o;
            o.x = f2bf(acc[i][0] * nf); o.y = f2bf(acc[i][1] * nf);
            o.z = f2bf(acc[i][2] * nf); o.w = f2bf(acc[i][3] * nf);
            *(ushort4*)&h2[(size_t)grow * 32 + c0] = o;
        }
    }
}

// ---------------- agg2: wave/node, uint2 loads = 8 edges/VMEM ---------------
// sub=lane>>3 (0..7) picks edge, c4=(lane&7)*4 picks 4-col group.
__global__ void k_agg32(const unsigned short* __restrict__ h,
                        const int* __restrict__ csrc,
                        const int* __restrict__ ostart, const int* __restrict__ oend,
                        const float* __restrict__ nI, const float* __restrict__ b2,
                        float* __restrict__ out, int n) {
    int node = blockIdx.x * 4 + (threadIdx.x >> 6);
    int lane = threadIdx.x & 63;
    if (node >= n) return;
    int s0 = ostart[node], s1 = oend[node];
    int sub = lane >> 3;
    int c4 = (lane & 7) * 4;
    float a0 = 0.f, a1 = 0.f, a2 = 0.f, a3 = 0.f;
    float d0 = 0.f, d1 = 0.f, d2 = 0.f, d3 = 0.f;
    int e = s0;
    for (; e + 15 < s1; e += 16) {               // 16 edges, 2 uint2 loads/lane
        int p0 = csrc[e + sub];
        int p1 = csrc[e + 8 + sub];
        uint2 u0 = *(const uint2*)&h[(size_t)p0 * 32 + c4];
        uint2 u1 = *(const uint2*)&h[(size_t)p1 * 32 + c4];
        a0 += __uint_as_float(u0.x << 16);
        a1 += __uint_as_float(u0.x & 0xFFFF0000u);
        a2 += __uint_as_float(u0.y << 16);
        a3 += __uint_as_float(u0.y & 0xFFFF0000u);
        d0 += __uint_as_float(u1.x << 16);
        d1 += __uint_as_float(u1.x & 0xFFFF0000u);
        d2 += __uint_as_float(u1.y << 16);
        d3 += __uint_as_float(u1.y & 0xFFFF0000u);
    }
    for (; e < s1; e += 8) {                     // tail, 8-edge groups guarded
        if (e + sub < s1) {
            int p = csrc[e + sub];
            uint2 u = *(const uint2*)&h[(size_t)p * 32 + c4];
            a0 += __uint_as_float(u.x << 16);
            a1 += __uint_as_float(u.x & 0xFFFF0000u);
            a2 += __uint_as_float(u.y << 16);
            a3 += __uint_as_float(u.y & 0xFFFF0000u);
        }
    }
    a0 += d0; a1 += d1; a2 += d2; a3 += d3;
    a0 += __shfl(a0, lane ^ 8, 64);
    a1 += __shfl(a1, lane ^ 8, 64);
    a2 += __shfl(a2, lane ^ 8, 64);
    a3 += __shfl(a3, lane ^ 8, 64);
    a0 += __shfl(a0, lane ^ 16, 64);
    a1 += __shfl(a1, lane ^ 16, 64);
    a2 += __shfl(a2, lane ^ 16, 64);
    a3 += __shfl(a3, lane ^ 16, 64);
    a0 += __shfl(a0, lane ^ 32, 64);
    a1 += __shfl(a1, lane ^ 32, 64);
    a2 += __shfl(a2, lane ^ 32, 64);
    a3 += __shfl(a3, lane ^ 32, 64);
    if (sub == 0) {
        float ni = nI[node];
        float4 o;
        o.x = fmaf(a0, ni, b2[c4 + 0]);
        o.y = fmaf(a1, ni, b2[c4 + 1]);
        o.z = fmaf(a2, ni, b2[c4 + 2]);
        o.w = fmaf(a3, ni, b2[c4 + 3]);
        *(float4*)&out[(size_t)node * 32 + c4] = o;
    }
}

extern "C" void kernel_launch(void* const* d_in, const int* in_sizes, int n_in,
                              void* d_out, int out_size, void* d_ws, size_t ws_size,
                              hipStream_t stream) {
    const float* x   = (const float*)d_in[0];  // [N,128]
    const int*   src = (const int*)d_in[1];    // [E]
    const int*   dst = (const int*)d_in[2];    // [E]
    const float* W1  = (const float*)d_in[3];  // [128,64]
    const float* b1  = (const float*)d_in[4];  // [64]
    const float* W2  = (const float*)d_in[5];  // [64,32]
    const float* b2  = (const float*)d_in[6];  // [32]
    float* out = (float*)d_out;                // [N,32]

    const int N = in_sizes[0] / 128;           // 100000
    const int E = in_sizes[1];                 // 1600000
    const int NB = (N + BNODES - 1) / BNODES;  // 782 buckets

    char* wsb = (char*)d_ws;
    int*   dO     = (int*)wsb;    wsb += (size_t)N * 4;          // \ one memset
    int*   bcur   = (int*)wsb;    wsb += (size_t)800 * 16 * 4;   // / (contiguous)
    float* nI     = (float*)wsb;  wsb += (size_t)N * 4;
    int*   ostart = (int*)wsb;    wsb += (size_t)N * 4;
    int*   oend   = (int*)wsb;    wsb += (size_t)N * 4;
    int*   csrc   = (int*)wsb;    wsb += (size_t)NB * CAP * 4;   // 8.0 MB
    unsigned short* h1 = (unsigned short*)wsb;
                                  wsb += (size_t)N * 64 * 2;     // 12.8 MB bf16
    float* x2     = (float*)wsb;  wsb += (size_t)N * 64 * 4;     // 25.6 MB
    unsigned short* h2 = h1;      // h1 dead after k_agg64
    int*   ebuf   = (int*)x2;     // 8 MB region; dead before agg64 writes x2

    // one memset covers dO + bcur (adjacent, both need zeros)
    hipMemsetAsync(dO, 0, ((size_t)N + 800 * 16) * sizeof(int), stream);

    // CSR build (degO fused into place phase 1)
    k_place<<<(E + 1023) / 1024, 512, 0, stream>>>(src, dst, bcur, ebuf, dO, E, NB);
    k_sort2<<<NB, 1024, 0, stream>>>(ebuf, bcur, csrc, ostart, oend, nI, N);

    // layer 1
    k_gemm1<<<(N + 63) / 64, 256, 0, stream>>>(x, W1, dO, h1, N);
    k_agg64<<<(N + 3) / 4, 256, 0, stream>>>(h1, csrc, ostart, oend, nI, b1, x2, N);

    // layer 2
    k_gemm2<<<(N + 127) / 128, 256, 0, stream>>>(x2, W2, dO, h2, N);
    k_agg32<<<(N + 3) / 4, 256, 0, stream>>>(h2, csrc, ostart, oend, nI, b2, out, N);
}

// Round 14
// 341.692 us; speedup vs baseline: 1.0773x; 1.0773x over previous
//
#include <hip/hip_runtime.h>
#include <hip/hip_bf16.h>

// GNN: 2-layer GraphConv (DGL norm='both'), N=100000, E=1600000.
// Round 14: recombine proven halves. k_place reverted to r12 config
// (1024thr x 4096-edge chunks, 391 blocks, fused dO — 86us measured; r13's
// 1563-block version fragmented ebuf runs to ~1.3 edges and write-amp rose
// 74->102MB, 115us: run length, not occupancy, was binding). Agg kernels
// keep r13's uint2 gathers (4 edges/VMEM agg64, 8 edges/VMEM agg32, ~-20us).

#define BSH 7                 // 128 nodes per bucket
#define BNODES 128
#define SRCMASK 0x1FFFF       // src < 131072
#define CAP 2560              // bucket capacity (mean 2048, sigma~45)

__device__ __forceinline__ unsigned short f2bf(float f) {
    unsigned int u = __float_as_uint(f);
    return (unsigned short)((u + 0x7FFFu + ((u >> 16) & 1u)) >> 16);  // RNE
}

// ---------------- place: bin edges into fixed-cap bucket regions ------------
// r12 config: 1024 thr, 4096-edge chunk (391 blocks -> ~5.2-edge runs per
// bucket per block; keeps ebuf store coalescing). Phase 1 also counts
// out-degree (fire-and-forget 100k-target atomics). bcur relative, zero-init.
__global__ __launch_bounds__(1024) void k_place(const int* __restrict__ src,
        const int* __restrict__ dst, int* __restrict__ bcur,
        int* __restrict__ ebuf, int* __restrict__ dO, int E, int NB) {
    __shared__ int lh[800], lbase[800];
    int t = threadIdx.x;
    int e0 = blockIdx.x * 4096;
    int e1 = min(e0 + 4096, E);
    for (int i = t; i < NB; i += 1024) lh[i] = 0;
    __syncthreads();
    for (int i = e0 + t; i < e1; i += 1024) {
        atomicAdd(&lh[dst[i] >> BSH], 1);
        atomicAdd(&dO[src[i]], 1);
    }
    __syncthreads();
    for (int i = t; i < NB; i += 1024) {
        int c = lh[i];
        if (c) lbase[i] = atomicAdd(&bcur[i * 16], c);
        lh[i] = 0;
    }
    __syncthreads();
    for (int i = e0 + t; i < e1; i += 1024) {
        int d = dst[i], b = d >> BSH;
        int pos = b * CAP + lbase[b] + atomicAdd(&lh[b], 1);
        ebuf[pos] = src[i] | ((d & (BNODES - 1)) << 17);
    }
}

// ---------------- sort2: bucket stream -> per-node CSR + ostart/oend + nI ---
__global__ __launch_bounds__(1024) void k_sort2(const int* __restrict__ ebuf,
        const int* __restrict__ bcur, int* __restrict__ csrc,
        int* __restrict__ ostart, int* __restrict__ oend,
        float* __restrict__ nI, int n) {
    __shared__ int cnt[BNODES], cur[BNODES], s[BNODES];
    int t = threadIdx.x, b = blockIdx.x;
    int e0 = b * CAP, e1 = e0 + bcur[b * 16];
    if (t < BNODES) cnt[t] = 0;
    __syncthreads();
    for (int i = e0 + t; i < e1; i += 1024)
        atomicAdd(&cnt[ebuf[i] >> 17], 1);
    __syncthreads();
    if (t < BNODES) s[t] = cnt[t];
    __syncthreads();
    for (int o = 1; o < BNODES; o <<= 1) {
        int u = (t < BNODES && t >= o) ? s[t - o] : 0;
        __syncthreads();
        if (t < BNODES) s[t] += u;
        __syncthreads();
    }
    if (t < BNODES) {
        int st = e0 + s[t] - cnt[t];
        cur[t] = st;
        int g = b * BNODES + t;
        if (g < n) {
            ostart[g] = st;
            oend[g] = e0 + s[t];
            nI[g] = rsqrtf(fmaxf((float)cnt[t], 1.0f));
        }
    }
    __syncthreads();
    for (int i = e0 + t; i < e1; i += 1024) {
        int p = ebuf[i];
        int pos = atomicAdd(&cur[p >> 17], 1);
        csrc[pos] = p & SRCMASK;
    }
}

// ---------------- GEMM1: h1(bf16) = (x*rsqrt(dO)) @ W1, 128->64 -------------
__global__ __launch_bounds__(256) void k_gemm1(const float* __restrict__ x,
                        const float* __restrict__ W1, const int* __restrict__ dO,
                        unsigned short* __restrict__ h1, int n) {
    __shared__ float sX[64 * 132];
    __shared__ float sW[128 * 64];
    const int t = threadIdx.x;
    {
        const float4* W4 = (const float4*)W1;
        float4* sW4 = (float4*)sW;
#pragma unroll
        for (int i = 0; i < 8; i++) sW4[t + 256 * i] = W4[t + 256 * i];
    }
    const int rowbase = blockIdx.x * 64;
    {
        const float4* x4 = (const float4*)x;
        float4* sX4 = (float4*)sX;
#pragma unroll
        for (int i = 0; i < 8; i++) {
            int f = t + 256 * i;
            int row = f >> 5, kc = f & 31;
            int grow = rowbase + row;
            float4 v = make_float4(0.f, 0.f, 0.f, 0.f);
            if (grow < n) v = x4[(size_t)grow * 32 + kc];
            sX4[row * 33 + kc] = v;
        }
    }
    __syncthreads();
    const int lane = t & 63, wv = t >> 6;
    const int rg = lane >> 2, cg = lane & 3;
    const int c0 = wv * 16 + cg * 4;
    float acc[4][4] = {};
    for (int kk = 0; kk < 128; kk += 4) {
        float xr[4][4], wr[4][4];
#pragma unroll
        for (int i = 0; i < 4; i++)
            *(float4*)xr[i] = *(const float4*)&sX[(rg + 16 * i) * 132 + kk];
#pragma unroll
        for (int j = 0; j < 4; j++)
            *(float4*)wr[j] = *(const float4*)&sW[(kk + j) * 64 + c0];
#pragma unroll
        for (int j = 0; j < 4; j++)
#pragma unroll
            for (int i = 0; i < 4; i++)
#pragma unroll
                for (int c = 0; c < 4; c++)
                    acc[i][c] = fmaf(xr[i][j], wr[j][c], acc[i][c]);
    }
#pragma unroll
    for (int i = 0; i < 4; i++) {
        int grow = rowbase + rg + 16 * i;
        if (grow < n) {
            float nf = rsqrtf(fmaxf((float)dO[grow], 1.0f));
            ushort4 o;
            o.x = f2bf(acc[i][0] * nf); o.y = f2bf(acc[i][1] * nf);
            o.z = f2bf(acc[i][2] * nf); o.w = f2bf(acc[i][3] * nf);
            *(ushort4*)&h1[(size_t)grow * 64 + c0] = o;
        }
    }
}

// ---------------- agg1: wave/node, uint2 loads = 4 edges/VMEM ---------------
__global__ void k_agg64(const unsigned short* __restrict__ h,
                        const int* __restrict__ csrc,
                        const int* __restrict__ ostart, const int* __restrict__ oend,
                        const float* __restrict__ nI, const float* __restrict__ b1,
                        float* __restrict__ x2, int n) {
    int node = blockIdx.x * 4 + (threadIdx.x >> 6);
    int lane = threadIdx.x & 63;
    if (node >= n) return;
    int s0 = ostart[node], s1 = oend[node];
    int sub = lane >> 4;
    int c4 = (lane & 15) * 4;
    float a0 = 0.f, a1 = 0.f, a2 = 0.f, a3 = 0.f;
    float d0 = 0.f, d1 = 0.f, d2 = 0.f, d3 = 0.f;
    int e = s0;
    for (; e + 7 < s1; e += 8) {                 // 8 edges, 2 uint2 loads/lane
        int p0 = csrc[e + sub];
        int p1 = csrc[e + 4 + sub];
        uint2 u0 = *(const uint2*)&h[(size_t)p0 * 64 + c4];
        uint2 u1 = *(const uint2*)&h[(size_t)p1 * 64 + c4];
        a0 += __uint_as_float(u0.x << 16);
        a1 += __uint_as_float(u0.x & 0xFFFF0000u);
        a2 += __uint_as_float(u0.y << 16);
        a3 += __uint_as_float(u0.y & 0xFFFF0000u);
        d0 += __uint_as_float(u1.x << 16);
        d1 += __uint_as_float(u1.x & 0xFFFF0000u);
        d2 += __uint_as_float(u1.y << 16);
        d3 += __uint_as_float(u1.y & 0xFFFF0000u);
    }
    for (; e < s1; e += 4) {                     // tail, guarded
        if (e + sub < s1) {
            int p = csrc[e + sub];
            uint2 u = *(const uint2*)&h[(size_t)p * 64 + c4];
            a0 += __uint_as_float(u.x << 16);
            a1 += __uint_as_float(u.x & 0xFFFF0000u);
            a2 += __uint_as_float(u.y << 16);
            a3 += __uint_as_float(u.y & 0xFFFF0000u);
        }
    }
    a0 += d0; a1 += d1; a2 += d2; a3 += d3;
    a0 += __shfl(a0, lane ^ 16, 64);
    a1 += __shfl(a1, lane ^ 16, 64);
    a2 += __shfl(a2, lane ^ 16, 64);
    a3 += __shfl(a3, lane ^ 16, 64);
    a0 += __shfl(a0, lane ^ 32, 64);
    a1 += __shfl(a1, lane ^ 32, 64);
    a2 += __shfl(a2, lane ^ 32, 64);
    a3 += __shfl(a3, lane ^ 32, 64);
    if (sub == 0) {
        float ni = nI[node];
        float4 o;
        o.x = fmaxf(fmaf(a0, ni, b1[c4 + 0]), 0.f);
        o.y = fmaxf(fmaf(a1, ni, b1[c4 + 1]), 0.f);
        o.z = fmaxf(fmaf(a2, ni, b1[c4 + 2]), 0.f);
        o.w = fmaxf(fmaf(a3, ni, b1[c4 + 3]), 0.f);
        *(float4*)&x2[(size_t)node * 64 + c4] = o;
    }
}

// ---------------- GEMM2: h2(bf16) = (x2*rsqrt(dO)) @ W2, 64->32 -------------
__global__ __launch_bounds__(256) void k_gemm2(const float* __restrict__ x2,
                        const float* __restrict__ W2, const int* __restrict__ dO,
                        unsigned short* __restrict__ h2, int n) {
    __shared__ float sX[128 * 68];
    __shared__ float sW[64 * 32];
    const int t = threadIdx.x;
    {
        const float4* W4 = (const float4*)W2;
        float4* sW4 = (float4*)sW;
#pragma unroll
        for (int i = 0; i < 2; i++) sW4[t + 256 * i] = W4[t + 256 * i];
    }
    const int rowbase = blockIdx.x * 128;
    {
        const float4* x4 = (const float4*)x2;
        float4* sX4 = (float4*)sX;
#pragma unroll
        for (int i = 0; i < 8; i++) {
            int f = t + 256 * i;
            int row = f >> 4, kc = f & 15;
            int grow = rowbase + row;
            float4 v = make_float4(0.f, 0.f, 0.f, 0.f);
            if (grow < n) v = x4[(size_t)grow * 16 + kc];
            sX4[row * 17 + kc] = v;
        }
    }
    __syncthreads();
    const int lane = t & 63, wv = t >> 6;
    const int whalf = wv >> 1, chalf = wv & 1;
    const int rg = lane >> 2, cg = lane & 3;
    const int c0 = chalf * 16 + cg * 4;
    const int rloc = whalf * 64 + rg;
    float acc[4][4] = {};
    for (int kk = 0; kk < 64; kk += 4) {
        float xr[4][4], wr[4][4];
#pragma unroll
        for (int i = 0; i < 4; i++)
            *(float4*)xr[i] = *(const float4*)&sX[(rloc + 16 * i) * 68 + kk];
#pragma unroll
        for (int j = 0; j < 4; j++)
            *(float4*)wr[j] = *(const float4*)&sW[(kk + j) * 32 + c0];
#pragma unroll
        for (int j = 0; j < 4; j++)
#pragma unroll
            for (int i = 0; i < 4; i++)
#pragma unroll
                for (int c = 0; c < 4; c++)
                    acc[i][c] = fmaf(xr[i][j], wr[j][c], acc[i][c]);
    }
#pragma unroll
    for (int i = 0; i < 4; i++) {
        int grow = rowbase + rloc + 16 * i;
        if (grow < n) {
            float nf = rsqrtf(fmaxf((float)dO[grow], 1.0f));
            ushort4 o;
            o.x = f2bf(acc[i][0] * nf); o.y = f2bf(acc[i][1] * nf);
            o.z = f2bf(acc[i][2] * nf); o.w = f2bf(acc[i][3] * nf);
            *(ushort4*)&h2[(size_t)grow * 32 + c0] = o;
        }
    }
}

// ---------------- agg2: wave/node, uint2 loads = 8 edges/VMEM ---------------
__global__ void k_agg32(const unsigned short* __restrict__ h,
                        const int* __restrict__ csrc,
                        const int* __restrict__ ostart, const int* __restrict__ oend,
                        const float* __restrict__ nI, const float* __restrict__ b2,
                        float* __restrict__ out, int n) {
    int node = blockIdx.x * 4 + (threadIdx.x >> 6);
    int lane = threadIdx.x & 63;
    if (node >= n) return;
    int s0 = ostart[node], s1 = oend[node];
    int sub = lane >> 3;
    int c4 = (lane & 7) * 4;
    float a0 = 0.f, a1 = 0.f, a2 = 0.f, a3 = 0.f;
    float d0 = 0.f, d1 = 0.f, d2 = 0.f, d3 = 0.f;
    int e = s0;
    for (; e + 15 < s1; e += 16) {               // 16 edges, 2 uint2 loads/lane
        int p0 = csrc[e + sub];
        int p1 = csrc[e + 8 + sub];
        uint2 u0 = *(const uint2*)&h[(size_t)p0 * 32 + c4];
        uint2 u1 = *(const uint2*)&h[(size_t)p1 * 32 + c4];
        a0 += __uint_as_float(u0.x << 16);
        a1 += __uint_as_float(u0.x & 0xFFFF0000u);
        a2 += __uint_as_float(u0.y << 16);
        a3 += __uint_as_float(u0.y & 0xFFFF0000u);
        d0 += __uint_as_float(u1.x << 16);
        d1 += __uint_as_float(u1.x & 0xFFFF0000u);
        d2 += __uint_as_float(u1.y << 16);
        d3 += __uint_as_float(u1.y & 0xFFFF0000u);
    }
    for (; e < s1; e += 8) {                     // tail, guarded
        if (e + sub < s1) {
            int p = csrc[e + sub];
            uint2 u = *(const uint2*)&h[(size_t)p * 32 + c4];
            a0 += __uint_as_float(u.x << 16);
            a1 += __uint_as_float(u.x & 0xFFFF0000u);
            a2 += __uint_as_float(u.y << 16);
            a3 += __uint_as_float(u.y & 0xFFFF0000u);
        }
    }
    a0 += d0; a1 += d1; a2 += d2; a3 += d3;
    a0 += __shfl(a0, lane ^ 8, 64);
    a1 += __shfl(a1, lane ^ 8, 64);
    a2 += __shfl(a2, lane ^ 8, 64);
    a3 += __shfl(a3, lane ^ 8, 64);
    a0 += __shfl(a0, lane ^ 16, 64);
    a1 += __shfl(a1, lane ^ 16, 64);
    a2 += __shfl(a2, lane ^ 16, 64);
    a3 += __shfl(a3, lane ^ 16, 64);
    a0 += __shfl(a0, lane ^ 32, 64);
    a1 += __shfl(a1, lane ^ 32, 64);
    a2 += __shfl(a2, lane ^ 32, 64);
    a3 += __shfl(a3, lane ^ 32, 64);
    if (sub == 0) {
        float ni = nI[node];
        float4 o;
        o.x = fmaf(a0, ni, b2[c4 + 0]);
        o.y = fmaf(a1, ni, b2[c4 + 1]);
        o.z = fmaf(a2, ni, b2[c4 + 2]);
        o.w = fmaf(a3, ni, b2[c4 + 3]);
        *(float4*)&out[(size_t)node * 32 + c4] = o;
    }
}

extern "C" void kernel_launch(void* const* d_in, const int* in_sizes, int n_in,
                              void* d_out, int out_size, void* d_ws, size_t ws_size,
                              hipStream_t stream) {
    const float* x   = (const float*)d_in[0];  // [N,128]
    const int*   src = (const int*)d_in[1];    // [E]
    const int*   dst = (const int*)d_in[2];    // [E]
    const float* W1  = (const float*)d_in[3];  // [128,64]
    const float* b1  = (const float*)d_in[4];  // [64]
    const float* W2  = (const float*)d_in[5];  // [64,32]
    const float* b2  = (const float*)d_in[6];  // [32]
    float* out = (float*)d_out;                // [N,32]

    const int N = in_sizes[0] / 128;           // 100000
    const int E = in_sizes[1];                 // 1600000
    const int NB = (N + BNODES - 1) / BNODES;  // 782 buckets

    char* wsb = (char*)d_ws;
    int*   dO     = (int*)wsb;    wsb += (size_t)N * 4;          // \ one memset
    int*   bcur   = (int*)wsb;    wsb += (size_t)800 * 16 * 4;   // / (contiguous)
    float* nI     = (float*)wsb;  wsb += (size_t)N * 4;
    int*   ostart = (int*)wsb;    wsb += (size_t)N * 4;
    int*   oend   = (int*)wsb;    wsb += (size_t)N * 4;
    int*   csrc   = (int*)wsb;    wsb += (size_t)NB * CAP * 4;   // 8.0 MB
    unsigned short* h1 = (unsigned short*)wsb;
                                  wsb += (size_t)N * 64 * 2;     // 12.8 MB bf16
    float* x2     = (float*)wsb;  wsb += (size_t)N * 64 * 4;     // 25.6 MB
    unsigned short* h2 = h1;      // h1 dead after k_agg64
    int*   ebuf   = (int*)x2;     // 8 MB region; dead before agg64 writes x2

    // one memset covers dO + bcur (adjacent, both need zeros)
    hipMemsetAsync(dO, 0, ((size_t)N + 800 * 16) * sizeof(int), stream);

    // CSR build (degO fused into place phase 1)
    k_place<<<(E + 4095) / 4096, 1024, 0, stream>>>(src, dst, bcur, ebuf, dO, E, NB);
    k_sort2<<<NB, 1024, 0, stream>>>(ebuf, bcur, csrc, ostart, oend, nI, N);

    // layer 1
    k_gemm1<<<(N + 63) / 64, 256, 0, stream>>>(x, W1, dO, h1, N);
    k_agg64<<<(N + 3) / 4, 256, 0, stream>>>(h1, csrc, ostart, oend, nI, b1, x2, N);

    // layer 2
    k_gemm2<<<(N + 127) / 128, 256, 0, stream>>>(x2, W2, dO, h2, N);
    k_agg32<<<(N + 3) / 4, 256, 0, stream>>>(h2, csrc, ostart, oend, nI, b2, out, N);
}